// Round 6
// baseline (215.529 us; speedup 1.0000x reference)
//
#include <hip/hip_runtime.h>

// GRUCell fused kernel for MI355X (gfx950), round 6.
// B=65536, I=128, H=256, CAT=384. f16 MFMA 16x16x32.
// R5 -> R6: R5 disproved the LDS-traffic theory (1.6x fewer LDS reads, slower).
// Real limiter: 72 barrier/waitcnt events per block with tiny MFMA clusters.
// R6: triple-buffered weight chunks -> ONE barrier per chunk (36 total);
// issue chunk s+2 right after top-of-body-s barrier (one barrier provably
// separates it from all reads of the buffer's previous occupant). x is no
// longer staged in LDS (A-frags k<128 read from global f32, L2-hot) so act
// LDS = h-only 32KB; 32KB + 3*16KB = 80KB -> 2 blocks/CU at NT=512 (R4's
// winning residency). vmcnt(2) per body; vmcnt(0) at the phase-2 tail.

#define BATCH 65536
#define ISZ   128
#define HSZ   256
#define CAT   384
#define BM    64
#define NT    512
#define HROWB 512              // act row bytes (256 f16, h part only)
#define ACT_B (BM * HROWB)     // 32768
#define CH_B  16384            // one weight chunk: 256 rows x 64 B (K=32)

using half8   = __attribute__((ext_vector_type(8))) _Float16;
using floatx4 = __attribute__((ext_vector_type(4))) float;

typedef unsigned int u32;
typedef __attribute__((address_space(1))) const u32 gu32;
typedef __attribute__((address_space(3))) u32 lu32;

__device__ __forceinline__ void gload16(const void* g, void* l) {
    __builtin_amdgcn_global_load_lds((gu32*)g, (lu32*)l, 16, 0, 0);
}

#define BAR()      __builtin_amdgcn_s_barrier()
#define SCHED0()   __builtin_amdgcn_sched_barrier(0)
#define WAIT_VM2() asm volatile("s_waitcnt vmcnt(2)" ::: "memory")
#define WAIT_VM0() asm volatile("s_waitcnt vmcnt(0)" ::: "memory")
#define WAIT_LG0() asm volatile("s_waitcnt lgkmcnt(0)" ::: "memory")
#define MFMA       __builtin_amdgcn_mfma_f32_16x16x32_f16

__device__ __forceinline__ float hsig(float x) {
    return fminf(fmaxf(x * (1.0f / 6.0f) + 0.5f, 0.0f), 1.0f);
}
__device__ __forceinline__ float htanh(float x) {
    return fminf(fmaxf(x, -1.0f), 1.0f);
}
__device__ __forceinline__ half8 cvt8(float4 v0, float4 v1) {
    half8 h;
    h[0] = (_Float16)v0.x; h[1] = (_Float16)v0.y;
    h[2] = (_Float16)v0.z; h[3] = (_Float16)v0.w;
    h[4] = (_Float16)v1.x; h[5] = (_Float16)v1.y;
    h[6] = (_Float16)v1.z; h[7] = (_Float16)v1.w;
    return h;
}

// ---- weight prep: f32 [256x384] row-major -> f16 same layout in d_ws ----
// ws layout: Wz rows 0..255, Wr 256..511, Wh 512..767
__global__ __launch_bounds__(256) void prep_weights(
    const float* __restrict__ Wz, const float* __restrict__ Wr,
    const float* __restrict__ Wh, _Float16* __restrict__ ws)
{
    const int m = blockIdx.y;
    const float* src = (m == 0) ? Wz : (m == 1) ? Wr : Wh;
    _Float16* dst = ws + (size_t)m * (HSZ * CAT);
    const int base = (blockIdx.x * 256 + threadIdx.x) * 8;
    float4 v0 = *(const float4*)(src + base);
    float4 v1 = *(const float4*)(src + base + 4);
    *(half8*)(dst + base) = cvt8(v0, v1);
}

// chunk c: c<24 -> matrix (c&1 ? Wr : Wz), k-slice c>>1 ; c>=24 -> Wh, slice c-24.
// buffer = c % 3. wbuf row n (64B): phys 16B slot p holds logical slot
// p ^ ((n>>1)&3). Wave-load i covers rows i*16 + (lane>>2), phys slot lane&3.
__device__ __forceinline__ void issue_chunk(const _Float16* __restrict__ wf,
                                            unsigned char* wbuf, int c,
                                            int w, int lane) {
    const _Float16* src = (c < 24) ? (wf + (c & 1) * (HSZ * CAT))
                                   : (wf + 2 * (HSZ * CAT));
    const int kk = (c < 24) ? (c >> 1) : (c - 24);
    unsigned char* dst = wbuf + (c % 3) * CH_B;
    #pragma unroll
    for (int ii = 0; ii < 2; ++ii) {
        const int i = w * 2 + ii;                  // wave-load 0..15
        const int n = i * 16 + (lane >> 2);        // weight row 0..255
        const int ss = (lane & 3) ^ ((n >> 1) & 3);
        gload16(src + n * CAT + kk * 32 + ss * 8, dst + i * 1024);
    }
}

// swizzled read of the 16B B-fragment for weight row n, k-slot lk
__device__ __forceinline__ half8 wread(const unsigned char* buf, int n, int lk) {
    return *(const half8*)(buf + n * 64 + ((lk ^ ((n >> 1) & 3)) << 4));
}

__global__ __launch_bounds__(NT, 4) void gru_kernel(
    const float* __restrict__ x, const float* __restrict__ h_prev,
    const float* __restrict__ b_z, const float* __restrict__ b_r,
    const float* __restrict__ b_h, const _Float16* __restrict__ wf,
    float* __restrict__ out)
{
    __shared__ __align__(16) unsigned char lds[ACT_B + 3 * CH_B];  // 80 KiB
    unsigned char* const act  = lds;        // h part of activations (swizzled)
    unsigned char* const wbuf = lds + ACT_B;

    const int t    = threadIdx.x;
    const int lane = t & 63;
    const int w    = t >> 6;
    const int mg   = w >> 2;        // rows mg*32 .. +31
    const int ng   = w & 3;         // cols ng*64 .. +63
    const int lr   = lane & 15;
    const int lk   = lane >> 4;
    const int row0 = blockIdx.x * BM;

    // prefetch weight chunks 0 (buf0) and 1 (buf1)
    issue_chunk(wf, wbuf, 0, w, lane);
    issue_chunk(wf, wbuf, 1, w, lane);

    // biases folded into accumulator init; b_h held for phase 2
    float bhv[4];
    floatx4 accz[2][4], accr[2][4];
    #pragma unroll
    for (int j = 0; j < 4; ++j) {
        const int col = ng * 64 + j * 16 + lr;
        const float vz = b_z[col];
        const float vr = b_r[col];
        bhv[j] = b_h[col];
        floatx4 tz = {vz, vz, vz, vz};
        floatx4 tr = {vr, vr, vr, vr};
        accz[0][j] = tz; accz[1][j] = tz;
        accr[0][j] = tr; accr[1][j] = tr;
    }

    // ---- stage h only (64x256 f32 -> f16), row-XOR swizzled ----
    for (int c = t; c < BM * 32; c += NT) {
        int row = c >> 5, kc = c & 31;
        const float* g = h_prev + (size_t)(row0 + row) * HSZ + kc * 8;
        float4 v0 = *(const float4*)g;
        float4 v1 = *(const float4*)(g + 4);
        *(half8*)(act + row * HROWB + ((kc * 16) ^ ((row & 7) << 4))) = cvt8(v0, v1);
    }
    WAIT_LG0(); SCHED0();
    BAR();   // h staged; chunks 0,1 effectively landed (staging loads drained them)

    const int rowA = mg * 32 + lr;
    const int asw  = (lr & 7) << 4;   // rowA&7 == (rowA+16)&7 == lr&7

    half8 a0, a1;

    // ---- phase 1: bodies z_k (chunk 2k, buf 2k%3) and r_k (chunk 2k+1).
    // One barrier per body. Body s issues chunk s+2 after its barrier: the
    // barrier separates that DMA from all reads of the buffer's previous
    // occupant (chunk s-1, read in body s-1). vmcnt(2) retires chunk s.
    #pragma unroll 1
    for (int kk = 0; kk < 12; ++kk) {
        // --- z body (s = 2kk) ---
        WAIT_VM2(); SCHED0(); BAR();
        if (kk < 4) {
            // x A-frags direct from global f32 (load BEFORE chunk issue so
            // their consumption waits vmcnt(2), not vmcnt(0))
            const float* g0 = x + (size_t)(row0 + rowA) * ISZ + kk * 32 + lk * 8;
            float4 u0 = *(const float4*)g0;
            float4 u1 = *(const float4*)(g0 + 4);
            float4 u2 = *(const float4*)(g0 + 16 * ISZ);
            float4 u3 = *(const float4*)(g0 + 16 * ISZ + 4);
            issue_chunk(wf, wbuf, 2 * kk + 2, w, lane);
            a0 = cvt8(u0, u1);
            a1 = cvt8(u2, u3);
        } else {
            issue_chunk(wf, wbuf, 2 * kk + 2, w, lane);
            const int off = (kk - 4) * 64 + lk * 16;
            a0 = *(const half8*)(act + rowA * HROWB        + (off ^ asw));
            a1 = *(const half8*)(act + (rowA + 16) * HROWB + (off ^ asw));
        }
        const unsigned char* bz = wbuf + ((2 * kk) % 3) * CH_B;
        __builtin_amdgcn_s_setprio(1);
        #pragma unroll
        for (int j = 0; j < 4; ++j) {
            half8 bf = wread(bz, ng * 64 + j * 16 + lr, lk);
            accz[0][j] = MFMA(a0, bf, accz[0][j], 0, 0, 0);
            accz[1][j] = MFMA(a1, bf, accz[1][j], 0, 0, 0);
        }
        __builtin_amdgcn_s_setprio(0);
        // --- r body (s = 2kk+1), A-frags reused ---
        WAIT_VM2(); SCHED0(); BAR();
        issue_chunk(wf, wbuf, 2 * kk + 3, w, lane);
        const unsigned char* brb = wbuf + ((2 * kk + 1) % 3) * CH_B;
        __builtin_amdgcn_s_setprio(1);
        #pragma unroll
        for (int j = 0; j < 4; ++j) {
            half8 bf = wread(brb, ng * 64 + j * 16 + lr, lk);
            accr[0][j] = MFMA(a0, bf, accr[0][j], 0, 0, 0);
            accr[1][j] = MFMA(a1, bf, accr[1][j], 0, 0, 0);
        }
        __builtin_amdgcn_s_setprio(0);
    }

    // ---- rescale: z = hsig(acc); r*h overwrites act in place (h from LDS).
    // Chunks 24,25 (h0,h1) are in flight during this window.
    BAR();   // all phase-1 LDS h reads complete everywhere before overwrite
    #pragma unroll
    for (int f = 0; f < 2; ++f) {
        #pragma unroll
        for (int j = 0; j < 4; ++j) {
            #pragma unroll
            for (int q = 0; q < 4; ++q) {
                const int row = mg * 32 + f * 16 + lk * 4 + q;  // C/D row=(l>>4)*4+q
                const int col = ng * 64 + j * 16 + lr;          //     col=l&15
                accz[f][j][q] = hsig(accz[f][j][q]);            // bias pre-added
                float rr = hsig(accr[f][j][q]);
                _Float16* hp = (_Float16*)(act + row * HROWB +
                                           ((col * 2) ^ ((row & 7) << 4)));
                float hv = (float)hp[0];
                hp[0] = (_Float16)(rr * hv);
            }
        }
    }
    WAIT_LG0(); SCHED0();   // own rescale writes landed before next barrier

    // ---- phase 2: h_tilde, chunks 24..35 in buf (24+kk)%3 ----
    floatx4 acch[2][4];
    #pragma unroll
    for (int j = 0; j < 4; ++j) {
        floatx4 th = {bhv[j], bhv[j], bhv[j], bhv[j]};
        acch[0][j] = th; acch[1][j] = th;
    }
    #pragma unroll 1
    for (int kk = 0; kk < 12; ++kk) {
        // Tail ledger: body kk=10 issues nothing ({34,35} outstanding, vmcnt(2)
        // waits 34 correctly); body kk=11 has only chunk 35 behind -> vmcnt(2)
        // would pass without waiting. Drain fully there (R4 lesson).
        if (kk < 11) { WAIT_VM2(); } else { WAIT_VM0(); }
        SCHED0(); BAR();
        if (kk < 4) {
            const float* g0 = x + (size_t)(row0 + rowA) * ISZ + kk * 32 + lk * 8;
            float4 u0 = *(const float4*)g0;
            float4 u1 = *(const float4*)(g0 + 4);
            float4 u2 = *(const float4*)(g0 + 16 * ISZ);
            float4 u3 = *(const float4*)(g0 + 16 * ISZ + 4);
            if (kk < 10) issue_chunk(wf, wbuf, 26 + kk, w, lane);
            a0 = cvt8(u0, u1);
            a1 = cvt8(u2, u3);
        } else {
            if (kk < 10) issue_chunk(wf, wbuf, 26 + kk, w, lane);
            const int off = (kk - 4) * 64 + lk * 16;
            a0 = *(const half8*)(act + rowA * HROWB        + (off ^ asw));
            a1 = *(const half8*)(act + (rowA + 16) * HROWB + (off ^ asw));
        }
        const unsigned char* bh_ = wbuf + ((24 + kk) % 3) * CH_B;
        __builtin_amdgcn_s_setprio(1);
        #pragma unroll
        for (int j = 0; j < 4; ++j) {
            half8 bf = wread(bh_, ng * 64 + j * 16 + lr, lk);
            acch[0][j] = MFMA(a0, bf, acch[0][j], 0, 0, 0);
            acch[1][j] = MFMA(a1, bf, acch[1][j], 0, 0, 0);
        }
        __builtin_amdgcn_s_setprio(0);
    }

    // ---- epilogue: h_next = z*h + (1-z)*hardtanh(.) ----
    #pragma unroll
    for (int f = 0; f < 2; ++f) {
        #pragma unroll
        for (int j = 0; j < 4; ++j) {
            #pragma unroll
            for (int q = 0; q < 4; ++q) {
                const int row = mg * 32 + f * 16 + lk * 4 + q;
                const int col = ng * 64 + j * 16 + lr;
                float ht = htanh(acch[f][j][q]);               // bias pre-added
                float zz = accz[f][j][q];
                float hv = h_prev[(size_t)(row0 + row) * HSZ + col];
                out[(size_t)(row0 + row) * HSZ + col] = zz * hv + (1.0f - zz) * ht;
            }
        }
    }
}

extern "C" void kernel_launch(void* const* d_in, const int* in_sizes, int n_in,
                              void* d_out, int out_size, void* d_ws, size_t ws_size,
                              hipStream_t stream) {
    const float* x  = (const float*)d_in[0];
    const float* h  = (const float*)d_in[1];
    const float* Wz = (const float*)d_in[2];
    const float* bz = (const float*)d_in[3];
    const float* Wr = (const float*)d_in[4];
    const float* br = (const float*)d_in[5];
    const float* Wh = (const float*)d_in[6];
    const float* bh = (const float*)d_in[7];
    _Float16* wf = (_Float16*)d_ws;   // 3*256*384*2 = 576 KiB scratch

    prep_weights<<<dim3(48, 3), 256, 0, stream>>>(Wz, Wr, Wh, wf);
    gru_kernel<<<dim3(BATCH / BM), NT, 0, stream>>>(
        x, h, bz, br, bh, wf, (float*)d_out);
}